// Round 7
// baseline (35.462 us; speedup 1.0000x reference)
//
#include <hip/hip_runtime.h>
#include <hip/hip_bf16.h>
#include <float.h>

#define HH 4096
#define WW 4096
#define RROWS 8   // output rows per thread

// 16B vector with only 4B alignment guarantee (for the x0±1 shifted loads;
// gfx950 global_load_dwordx4 supports dword alignment).
typedef float f4u __attribute__((ext_vector_type(4), aligned(4)));

__global__ __launch_bounds__(256) void nms_kernel(
    const float* __restrict__ rel,
    const float* __restrict__ rep,
    const float* __restrict__ rel_thr_p,
    const float* __restrict__ rep_thr_p,
    int* __restrict__ out)
{
    // XCD-chunked bijective swizzle (nwg = 2048, %8 == 0), column-major walk.
    const int bid  = blockIdx.x;
    const int xcd  = bid & 7;
    const int wgid = xcd * 256 + (bid >> 3);
    const int bx   = wgid >> 9;           // 0..3
    const int by   = wgid & 511;          // 0..511

    const int x0    = (bx * 256 + threadIdx.x) * 4;
    const int ybase = by * RROWS;
    const bool edgeL = (x0 == 0);
    const bool edgeR = (x0 + 4 == WW);

    const float rel_thr = *rel_thr_p;
    const float rep_thr = *rep_thr_p;
    const float NEG = -FLT_MAX;

    // ---- batch-issue all aligned loads: 10 rep center rows + 8 rel rows ----
    float4 v[RROWS + 2];
    #pragma unroll
    for (int r = 0; r < RROWS + 2; ++r) {
        const int yy = ybase + r - 1;
        if (yy >= 0 && yy < HH)           // wave-uniform
            v[r] = *reinterpret_cast<const float4*>(rep + (size_t)yy * WW + x0);
        else
            v[r] = make_float4(NEG, NEG, NEG, NEG);
    }

    float4 rl[RROWS];
    #pragma unroll
    for (int i = 0; i < RROWS; ++i)
        rl[i] = *reinterpret_cast<const float4*>(rel + (size_t)(ybase + i) * WW + x0);

    // ---- horizontal 3-tap max per row: two shifted loads + v_max3, no shfl ----
    float4 hm[RROWS + 2];
    #pragma unroll
    for (int r = 0; r < RROWS + 2; ++r) {
        const int yy = ybase + r - 1;
        if (yy < 0 || yy >= HH) {         // wave-uniform
            hm[r] = make_float4(NEG, NEG, NEG, NEG);
            continue;
        }
        const float* row = rep + (size_t)yy * WW;
        const f4u Lv = *reinterpret_cast<const f4u*>(row + (edgeL ? x0 : x0 - 1));
        const f4u Rv = *reinterpret_cast<const f4u*>(row + (edgeR ? x0 : x0 + 1));
        // branchless edge recomposition: when clamped, Lv/Rv equal the center
        // vector; shift and pad with NEG via cndmask.
        float4 L, R;
        L.x = edgeL ? NEG  : Lv.x;  L.y = edgeL ? Lv.x : Lv.y;
        L.z = edgeL ? Lv.y : Lv.z;  L.w = edgeL ? Lv.z : Lv.w;
        R.x = edgeR ? Rv.y : Rv.x;  R.y = edgeR ? Rv.z : Rv.y;
        R.z = edgeR ? Rv.w : Rv.z;  R.w = edgeR ? NEG  : Rv.w;
        hm[r].x = fmaxf(fmaxf(L.x, v[r].x), R.x);   // -> v_max3_f32
        hm[r].y = fmaxf(fmaxf(L.y, v[r].y), R.y);
        hm[r].z = fmaxf(fmaxf(L.z, v[r].z), R.z);
        hm[r].w = fmaxf(fmaxf(L.w, v[r].w), R.w);
    }

    // ---- vertical max, compare, store ----
    #pragma unroll
    for (int i = 0; i < RROWS; ++i) {
        const int y = ybase + i;
        const float4 c = v[i + 1];

        const float m0 = fmaxf(fmaxf(hm[i].x, hm[i + 1].x), hm[i + 2].x);
        const float m1 = fmaxf(fmaxf(hm[i].y, hm[i + 1].y), hm[i + 2].y);
        const float m2 = fmaxf(fmaxf(hm[i].z, hm[i + 1].z), hm[i + 2].z);
        const float m3 = fmaxf(fmaxf(hm[i].w, hm[i + 1].w), hm[i + 2].w);

        int4 o;
        o.x = (c.x == m0 && c.x >= rep_thr && rl[i].x >= rel_thr) ? 1 : 0;
        o.y = (c.y == m1 && c.y >= rep_thr && rl[i].y >= rel_thr) ? 1 : 0;
        o.z = (c.z == m2 && c.z >= rep_thr && rl[i].z >= rel_thr) ? 1 : 0;
        o.w = (c.w == m3 && c.w >= rep_thr && rl[i].w >= rel_thr) ? 1 : 0;

        *reinterpret_cast<int4*>(out + (size_t)y * WW + x0) = o;
    }
}

extern "C" void kernel_launch(void* const* d_in, const int* in_sizes, int n_in,
                              void* d_out, int out_size, void* d_ws, size_t ws_size,
                              hipStream_t stream)
{
    const float* rel       = (const float*)d_in[0];
    const float* rep       = (const float*)d_in[1];
    const float* rel_thr_p = (const float*)d_in[2];
    const float* rep_thr_p = (const float*)d_in[3];
    int* out = (int*)d_out;

    dim3 block(256, 1, 1);
    dim3 grid(2048, 1, 1);   // 4 x-tiles * 512 y-tiles, swizzled in-kernel
    nms_kernel<<<grid, block, 0, stream>>>(rel, rep, rel_thr_p, rep_thr_p, out);
}

// Round 8
// 33.567 us; speedup vs baseline: 1.0564x; 1.0564x over previous
//
#include <hip/hip_runtime.h>
#include <hip/hip_bf16.h>
#include <float.h>

#define HH 4096
#define WW 4096
#define RROWS 8   // output rows per thread

// Structural note (roofline): logical traffic is compulsory-minimal at
// 192 MB (rep 64 + rel 64 read, out 64 write). Measured floor ~34 us =
// 5.6 TB/s logical composite (HBM ~4.1 TB/s + L3 hits), the mixed R+W
// memory-system ceiling. Occupancy (73%->24%), MLP (6x), predication,
// NT hints, and shifted-load variants all land 34-37 us -> memory-bound.

__global__ __launch_bounds__(256) void nms_kernel(
    const float* __restrict__ rel,
    const float* __restrict__ rep,
    const float* __restrict__ rel_thr_p,
    const float* __restrict__ rep_thr_p,
    int* __restrict__ out)
{
    // XCD-chunked bijective swizzle (nwg = 2048, %8 == 0), then column-major
    // tile walk: halo rows of vertically-adjacent tiles stay same-XCD L2-hot.
    const int bid  = blockIdx.x;          // 0..2047
    const int xcd  = bid & 7;
    const int wgid = xcd * 256 + (bid >> 3);
    const int bx   = wgid >> 9;           // / 512  -> 0..3
    const int by   = wgid & 511;          // % 512

    const int x0    = (bx * 256 + threadIdx.x) * 4;   // 4 px/thread in x
    const int ybase = by * RROWS;
    const int lane  = threadIdx.x & 63;

    const float rel_thr = *rel_thr_p;
    const float rep_thr = *rep_thr_p;
    const float NEG = -FLT_MAX;

    // ---- batch-issue ALL loads first: 10 rep rows + 8 rel rows in flight ----
    float4 v[RROWS + 2];
    #pragma unroll
    for (int r = 0; r < RROWS + 2; ++r) {
        const int yy = ybase + r - 1;
        if (yy >= 0 && yy < HH)    // wave-uniform (only first/last tile rows)
            v[r] = *reinterpret_cast<const float4*>(rep + (size_t)yy * WW + x0);
        else
            v[r] = make_float4(NEG, NEG, NEG, NEG);
    }

    float4 rl[RROWS];
    #pragma unroll
    for (int i = 0; i < RROWS; ++i)
        rl[i] = *reinterpret_cast<const float4*>(rel + (size_t)(ybase + i) * WW + x0);

    // ---- horizontal 3-tap max per row (in-register, shfl for lane edges) ----
    float4 hm[RROWS + 2];
    #pragma unroll
    for (int r = 0; r < RROWS + 2; ++r) {
        const int yy = ybase + r - 1;
        float left  = __shfl_up(v[r].w, 1);
        float right = __shfl_down(v[r].x, 1);
        if (lane == 0)
            left  = (x0 > 0 && yy >= 0 && yy < HH)
                  ? rep[(size_t)yy * WW + x0 - 1] : NEG;
        if (lane == 63)
            right = (x0 + 4 < WW && yy >= 0 && yy < HH)
                  ? rep[(size_t)yy * WW + x0 + 4] : NEG;
        hm[r].x = fmaxf(fmaxf(left,    v[r].x), v[r].y);
        hm[r].y = fmaxf(fmaxf(v[r].x,  v[r].y), v[r].z);
        hm[r].z = fmaxf(fmaxf(v[r].y,  v[r].z), v[r].w);
        hm[r].w = fmaxf(fmaxf(v[r].z,  v[r].w), right);
    }

    // ---- vertical max, compare, store ----
    #pragma unroll
    for (int i = 0; i < RROWS; ++i) {
        const int y = ybase + i;
        const float4 c = v[i + 1];

        const float m0 = fmaxf(fmaxf(hm[i].x, hm[i + 1].x), hm[i + 2].x);
        const float m1 = fmaxf(fmaxf(hm[i].y, hm[i + 1].y), hm[i + 2].y);
        const float m2 = fmaxf(fmaxf(hm[i].z, hm[i + 1].z), hm[i + 2].z);
        const float m3 = fmaxf(fmaxf(hm[i].w, hm[i + 1].w), hm[i + 2].w);

        int4 o;
        o.x = (c.x == m0 && c.x >= rep_thr && rl[i].x >= rel_thr) ? 1 : 0;
        o.y = (c.y == m1 && c.y >= rep_thr && rl[i].y >= rel_thr) ? 1 : 0;
        o.z = (c.z == m2 && c.z >= rep_thr && rl[i].z >= rel_thr) ? 1 : 0;
        o.w = (c.w == m3 && c.w >= rep_thr && rl[i].w >= rel_thr) ? 1 : 0;

        *reinterpret_cast<int4*>(out + (size_t)y * WW + x0) = o;
    }
}

extern "C" void kernel_launch(void* const* d_in, const int* in_sizes, int n_in,
                              void* d_out, int out_size, void* d_ws, size_t ws_size,
                              hipStream_t stream)
{
    const float* rel       = (const float*)d_in[0];
    const float* rep       = (const float*)d_in[1];
    const float* rel_thr_p = (const float*)d_in[2];
    const float* rep_thr_p = (const float*)d_in[3];
    int* out = (int*)d_out;

    dim3 block(256, 1, 1);
    dim3 grid(2048, 1, 1);   // 4 x-tiles * 512 y-tiles, swizzled in-kernel
    nms_kernel<<<grid, block, 0, stream>>>(rel, rep, rel_thr_p, rep_thr_p, out);
}